// Round 4
// baseline (7850.325 us; speedup 1.0000x reference)
//
#include <hip/hip_runtime.h>
#include <math.h>

#define Bsz 512
#define Nn  199
#define Ff  64
#define Uu  64
#define Hh  4
#define LDO 455   // Hh*Uu + Nn
#define NT  512   // threads per block (8 waves)
#define RPG 4     // rows per group
#define NG  50    // ceil(199/4) row-groups

typedef float f4_t __attribute__((ext_vector_type(4)));

// ---------------- prep: AW[h][n][m] = A[n][m] * W[h][n][m]; Abits[m][k] bitmask of A row m
__global__ __launch_bounds__(256)
void dgc_prep(const float* __restrict__ A, const float* __restrict__ W,
              float* __restrict__ AW, unsigned long long* __restrict__ Abits)
{
    int i = blockIdx.x * 256 + threadIdx.x;
    if (i < Hh * Nn * Nn) {
        int nm = i % (Nn * Nn);
        AW[i] = W[i] * A[nm];
    }
    if (i < Nn * 4) {
        int m = i >> 2, k = i & 3;
        unsigned long long bits = 0ull;
        #pragma unroll
        for (int l = 0; l < 64; ++l) {
            int j = k * 64 + l;
            if (j < Nn && A[m * Nn + j] != 0.0f) bits |= (1ull << l);
        }
        Abits[i] = bits;
    }
}

// ---------------- main fused kernel: one block per (b,h), 8 waves
__global__ __launch_bounds__(NT, 1)
void dgc_main(const float* __restrict__ X, const float* __restrict__ AW,
              const unsigned long long* __restrict__ AbitsG,
              const float* __restrict__ Kg, const float* __restrict__ Tg,
              const float* __restrict__ b1g, const float* __restrict__ b2g,
              float* __restrict__ out)
{
    // LDS: 51200 + 52000 + 16384 + 6400 + 26112 = 152096 B (< 160 KiB, 1 block/CU, 8 waves)
    __shared__ __align__(16) float Xs[Nn + 1][Ff];     // X_b, padded row 199 (zeroed)
    __shared__ __align__(16) float Ks[Ff + 1][200];    // kernel_h [f][j], pitch 200, pads zeroed
    __shared__ __align__(16) float Ts[Ff][Uu];         // T_h
    __shared__ unsigned long long Ab[200][4];          // adjacency row bitmasks
    __shared__ __align__(16) float sc[8][RPG][204];    // per-wave scratch: feat/mask/node rows

    const int tid  = threadIdx.x;
    const int lane = tid & 63;
    const int w    = __builtin_amdgcn_readfirstlane(tid >> 6);
    const int b    = blockIdx.x >> 2;
    const int h    = blockIdx.x & 3;

    // ---- stage X_b (coalesced float4): 199*64/4 = 3184 f4
    {
        const f4_t* src = (const f4_t*)(X + (size_t)b * Nn * Ff);
        f4_t* dst = (f4_t*)&Xs[0][0];
        #pragma unroll
        for (int it = 0; it < 7; ++it) {
            int idx = tid + it * NT;
            if (idx < Nn * Ff / 4) dst[idx] = src[idx];
        }
        if (tid < Ff) Xs[Nn][tid] = 0.0f;  // zero pad row (node-phase overread)
    }
    // ---- stage kernel_h into [f][j] pitch-200
    {
        const float* src = Kg + (size_t)h * Ff * Nn;
        for (int i = tid; i < Ff * Nn; i += NT) {
            int f = i / Nn, j = i - f * Nn;
            Ks[f][j] = src[i];
        }
        if (tid < Ff)  Ks[tid][199] = 0.0f;   // pad col
        if (tid < 200) Ks[Ff][tid]  = 0.0f;   // pad row (never hit by f-quad loop, but safe)
    }
    // ---- stage T_h: 4096 floats = 1024 f4
    {
        const f4_t* src = (const f4_t*)(Tg + (size_t)h * Ff * Uu);
        f4_t* dst = (f4_t*)&Ts[0][0];
        #pragma unroll
        for (int it = 0; it < 2; ++it) dst[tid + it * NT] = src[tid + it * NT];
    }
    // ---- stage adjacency bitmasks (796 u64) -- strided: 796 > NT
    for (int i = tid; i < Nn * 4; i += NT) ((unsigned long long*)Ab)[i] = AbitsG[i];

    // ---- per-thread bias registers
    float b1v[4];
    #pragma unroll
    for (int k = 0; k < 4; ++k) {
        int j = lane + 64 * k;
        b1v[k] = (j < Nn) ? b1g[h * Nn + j] : 0.0f;
    }
    const float b2v = b2g[h * Uu + lane];

    __syncthreads();

    const float* AWh  = AW + (size_t)h * Nn * Nn;
    float*       outb = out + (size_t)b * Nn * LDO;

    // 50 row-groups of 4 (last has 3), round-robined over the 8 waves; no barriers needed.
    for (int g = w; g < NG; g += 8) {
        const int m0 = __builtin_amdgcn_readfirstlane(g * RPG);
        const int R  = min(RPG, Nn - m0);

        // ---- Phase A: feat rows m0..m0+3 (lane = f). feat[m,f] = sum_n AW[n,m]*X[n,f]
        float fa[RPG];
        #pragma unroll
        for (int r = 0; r < RPG; ++r) fa[r] = 0.0f;
        #pragma unroll 4
        for (int n = 0; n < Nn; ++n) {
            float xv = Xs[n][lane];
            int base = __builtin_amdgcn_readfirstlane(n * Nn + m0);  // -> scalar loads of AW chunk
            #pragma unroll
            for (int r = 0; r < RPG; ++r) fa[r] = fmaf(AWh[base + r], xv, fa[r]);
        }
        #pragma unroll
        for (int r = 0; r < RPG; ++r) sc[w][r][lane] = fa[r];

        // ---- Phase B: dense tile, lane covers j = lane+64k, k<4; accumulate over f
        float d[RPG][4];
        #pragma unroll
        for (int r = 0; r < RPG; ++r)
            #pragma unroll
            for (int k = 0; k < 4; ++k) d[r][k] = 0.0f;
        for (int f = 0; f < Ff; f += 4) {
            f4_t fr[RPG];
            #pragma unroll
            for (int r = 0; r < RPG; ++r) fr[r] = *(const f4_t*)&sc[w][r][f];  // uniform b128
            float kv[4][4];
            #pragma unroll
            for (int df = 0; df < 4; ++df)
                #pragma unroll
                for (int k = 0; k < 4; ++k) kv[df][k] = Ks[f + df][lane + 64 * k];
            #pragma unroll
            for (int r = 0; r < RPG; ++r)
                #pragma unroll
                for (int df = 0; df < 4; ++df)
                    #pragma unroll
                    for (int k = 0; k < 4; ++k)
                        d[r][k] = fmaf(fr[r][df], kv[df][k], d[r][k]);
        }

        // ---- Phase C: masked softmax per row; write mask row to scratch (and h==3 slice to out)
        for (int r = 0; r < R; ++r) {
            int m = m0 + r;
            float lg[4]; bool val[4];
            #pragma unroll
            for (int k = 0; k < 4; ++k) {
                unsigned long long ab = Ab[m][k];
                int j = lane + 64 * k;
                val[k] = (j < Nn) && ((ab >> lane) & 1ull);
                lg[k]  = d[r][k] + b1v[k];
            }
            float mx = -INFINITY;
            #pragma unroll
            for (int k = 0; k < 4; ++k) if (val[k]) mx = fmaxf(mx, lg[k]);
            #pragma unroll
            for (int off = 32; off; off >>= 1) mx = fmaxf(mx, __shfl_xor(mx, off, 64));
            float e[4], s = 0.0f;
            #pragma unroll
            for (int k = 0; k < 4; ++k) {
                e[k] = val[k] ? expf(lg[k] - mx) : 0.0f;  // masked -> exactly 0, as reference
                s += e[k];
            }
            #pragma unroll
            for (int off = 32; off; off >>= 1) s += __shfl_xor(s, off, 64);
            float inv = 1.0f / s;
            #pragma unroll
            for (int k = 0; k < 4; ++k) {
                float mv = e[k] * inv;
                int j = lane + 64 * k;
                if (j < 200) sc[w][r][j] = mv;                       // cols 0..199 (199 stays 0)
                if (h == 3 && j < Nn) outb[m * LDO + 256 + j] = mv;  // last head's mask
            }
        }

        // ---- Phase D: node rows (lane = f). node[m,f] = sum_j mask[m,j]*X[j,f]
        float nd[RPG];
        #pragma unroll
        for (int r = 0; r < RPG; ++r) nd[r] = 0.0f;
        for (int j = 0; j < 200; j += 4) {
            float xv[4];
            #pragma unroll
            for (int dj = 0; dj < 4; ++dj) xv[dj] = Xs[j + dj][lane];
            #pragma unroll
            for (int r = 0; r < RPG; ++r) {
                f4_t mv = *(const f4_t*)&sc[w][r][j];  // uniform b128
                #pragma unroll
                for (int dj = 0; dj < 4; ++dj) nd[r] = fmaf(mv[dj], xv[dj], nd[r]);
            }
        }

        // ---- Phase E: out rows (lane = u). out[m,u] = bias2[u] + sum_f node[m,f]*T[f,u]
        #pragma unroll
        for (int r = 0; r < RPG; ++r) sc[w][r][lane] = nd[r];  // node rows -> scratch (mask consumed)
        float o[RPG];
        #pragma unroll
        for (int r = 0; r < RPG; ++r) o[r] = b2v;
        for (int f = 0; f < Ff; f += 4) {
            float tv[4];
            #pragma unroll
            for (int df = 0; df < 4; ++df) tv[df] = Ts[f + df][lane];
            #pragma unroll
            for (int r = 0; r < RPG; ++r) {
                f4_t nv = *(const f4_t*)&sc[w][r][f];  // uniform b128
                #pragma unroll
                for (int df = 0; df < 4; ++df) o[r] = fmaf(nv[df], tv[df], o[r]);
            }
        }
        #pragma unroll
        for (int r = 0; r < RPG; ++r) {
            int m = m0 + r;
            if (m < Nn) outb[m * LDO + h * 64 + lane] = o[r];
        }
    }
}

extern "C" void kernel_launch(void* const* d_in, const int* in_sizes, int n_in,
                              void* d_out, int out_size, void* d_ws, size_t ws_size,
                              hipStream_t stream)
{
    const float* X  = (const float*)d_in[0];
    const float* A  = (const float*)d_in[1];
    const float* W  = (const float*)d_in[2];
    const float* Kg = (const float*)d_in[3];
    const float* Tg = (const float*)d_in[4];
    const float* b1 = (const float*)d_in[5];
    const float* b2 = (const float*)d_in[6];
    float* out = (float*)d_out;

    float* AW = (float*)d_ws;                                                 // 158404 floats
    unsigned long long* Abits = (unsigned long long*)((char*)d_ws + 633616);  // 796 u64

    dgc_prep<<<dim3((Hh * Nn * Nn + 255) / 256), dim3(256), 0, stream>>>(A, W, AW, Abits);
    dgc_main<<<dim3(Bsz * Hh), dim3(NT), 0, stream>>>(X, AW, Abits, Kg, Tg, b1, b2, out);
}